// Round 5
// baseline (1020.028 us; speedup 1.0000x reference)
//
#include <hip/hip_runtime.h>
#include <hip/hip_bf16.h>
#include <math.h>

// ---------------------------------------------------------------------------
// GINE x3 + global_add_pool + Bayesian head.
// Round 5: aggregation = fused MFMA edge-projection (K=16 GEMM) + LDS tile +
// run-length segment-sum with f32 atomics. h stays bf16, agg f32.
// ---------------------------------------------------------------------------

#define THREADS 256

typedef __attribute__((ext_vector_type(8))) short bf16x8;
typedef __attribute__((ext_vector_type(4))) float f32x4;

__device__ __forceinline__ unsigned short f2bf(float x) {
    __hip_bfloat16 h = __float2bfloat16(x);
    return __builtin_bit_cast(unsigned short, h);
}
__device__ __forceinline__ float bflo(unsigned u) {
    return __builtin_bit_cast(float, u << 16);
}
__device__ __forceinline__ float bfhi(unsigned u) {
    return __builtin_bit_cast(float, u & 0xffff0000u);
}
__device__ __forceinline__ float bf2f(unsigned short u) {
    return __builtin_bit_cast(float, (unsigned)u << 16);
}
__device__ __forceinline__ unsigned pk(float a, float b) {
    return (unsigned)f2bf(a) | ((unsigned)f2bf(b) << 16);
}

// ---------------- CSR build: histogram of dst
__global__ __launch_bounds__(THREADS) void hist_kernel(
    const int* __restrict__ ei, int* __restrict__ deg, int E)
{
    int e = blockIdx.x * THREADS + threadIdx.x;
    if (e < E) atomicAdd(&deg[ei[E + e]], 1);
}

// ---------------- CSR build: single-block exclusive scan -> rowptr[0..n]
__global__ __launch_bounds__(1024) void scan_kernel(
    const int* __restrict__ deg, int* __restrict__ rowptr, int n)
{
    __shared__ int s[1024];
    __shared__ int carry_s;
    const int t = threadIdx.x;
    if (t == 0) carry_s = 0;
    __syncthreads();
    for (int base = 0; base < n; base += 1024) {
        int i = base + t;
        s[t] = (i < n) ? deg[i] : 0;
        __syncthreads();
        for (int off = 1; off < 1024; off <<= 1) {
            int add = (t >= off) ? s[t - off] : 0;
            __syncthreads();
            s[t] += add;
            __syncthreads();
        }
        int incl = s[t];
        int carry = carry_s;
        if (i < n) rowptr[i + 1] = carry + incl;
        __syncthreads();
        if (t == 1023) carry_s = carry + incl;
        __syncthreads();
    }
    if (t == 0) rowptr[0] = 0;
}

// ---------------- CSR build: scatter edge ids into slots (also csr_dst)
__global__ __launch_bounds__(THREADS) void fill_kernel(
    const int* __restrict__ ei, const int* __restrict__ rowptr,
    int* __restrict__ cursor, int* __restrict__ csr_src,
    int* __restrict__ csr_dst, int* __restrict__ csr_eid, int E)
{
    int e = blockIdx.x * THREADS + threadIdx.x;
    if (e >= E) return;
    int s = ei[e], d = ei[E + e];
    int pos  = atomicAdd(&cursor[d], 1);
    int slot = rowptr[d] + pos;
    csr_src[slot] = s;
    csr_dst[slot] = d;
    csr_eid[slot] = e;
}

// ---------------- edge_attr -> bf16 [E][16] in CSR slot order
__global__ __launch_bounds__(THREADS) void easort_kernel(
    const float* __restrict__ edge_attr, const int* __restrict__ csr_eid,
    unsigned short* __restrict__ ea16, int E)
{
    int s = blockIdx.x * THREADS + threadIdx.x;
    if (s >= E) return;
    int eid = csr_eid[s];
    const float4* a = (const float4*)(edge_attr + (size_t)eid * 16);
    float4 a0 = a[0], a1 = a[1], a2 = a[2], a3 = a[3];
    uint4* d = (uint4*)(ea16 + (size_t)s * 16);
    d[0] = make_uint4(pk(a0.x, a0.y), pk(a0.z, a0.w), pk(a1.x, a1.y), pk(a1.z, a1.w));
    d[1] = make_uint4(pk(a2.x, a2.y), pk(a2.z, a2.w), pk(a3.x, a3.y), pk(a3.z, a3.w));
}

// ---------------- x -> bf16 copy
__global__ __launch_bounds__(THREADS) void xprep_kernel(
    const float* __restrict__ x, unsigned short* __restrict__ xbf, int n4)
{
    int i = blockIdx.x * THREADS + threadIdx.x;
    if (i >= n4) return;
    float4 v = ((const float4*)x)[i];
    uint2 p;
    p.x = pk(v.x, v.y);
    p.y = pk(v.z, v.w);
    ((uint2*)xbf)[i] = p;
}

// ---------------- We[16][D] f32 -> Wtp[D][32] bf16 (k 16..31 zero)
__global__ __launch_bounds__(THREADS) void wetrans_kernel(
    const float* __restrict__ We, unsigned short* __restrict__ Wtp, int D)
{
    int f = blockIdx.x * THREADS + threadIdx.x;
    if (f >= D) return;
#pragma unroll
    for (int k = 0; k < 16; k++) Wtp[f * 32 + k] = f2bf(We[k * D + f]);
#pragma unroll
    for (int k = 16; k < 32; k++) Wtp[f * 32 + k] = 0;
}

// ---------------- fused MFMA aggregation:
// phase1: proj[f][e] = ea[e][:16] @ We[:,f]  (MFMA, K padded to 32)
// phase2: agg[dst][f] += relu(h[src][f] + proj + be[f])  (run-length + atomics)
template<int D>
__global__ __launch_bounds__(THREADS) void edge_agg_kernel(
    const unsigned short* __restrict__ hbf,   // [N][D] bf16
    const unsigned short* __restrict__ ea16,  // [E][16] bf16, CSR order
    const int* __restrict__ csr_src,          // [E]
    const int* __restrict__ csr_dst,          // [E] (non-decreasing)
    const unsigned short* __restrict__ Wtp,   // [D][32] bf16, k>=16 zero
    const float* __restrict__ be,             // [D]
    float* __restrict__ agg,                  // [N][D] f32, pre-zeroed
    int E)
{
    constexpr int EPB = (D == 128) ? 128 : 64;   // edges per block
    constexpr int LDF = D + 8;                   // padded LDS feature stride
    __shared__ unsigned short msg[EPB * LDF];
    __shared__ int src_s[EPB], dst_s[EPB];

    const int t    = threadIdx.x;
    const int e0   = blockIdx.x * EPB;
    const int lane = t & 63, wid = t >> 6;
    const int l15  = lane & 15, lgr = lane >> 4;

    // stage src/dst for phase 2
    for (int i = t; i < EPB; i += THREADS) {
        int e = e0 + i;
        src_s[i] = (e < E) ? csr_src[e] : 0;
        dst_s[i] = (e < E) ? csr_dst[e] : 0;
    }

    // ---- phase 1: MFMA projection, C[feature][edge]
    const int fb = (D == 128) ? (wid & 1) * 64 : wid * 64;   // feature base
    const int eb = (D == 128) ? (wid >> 1) * 64 : 0;         // edge base

    bf16x8 af[4];
#pragma unroll
    for (int mf = 0; mf < 4; mf++)
        af[mf] = *(const bf16x8*)(Wtp + (size_t)(fb + mf * 16 + l15) * 32 + lgr * 8);

    f32x4 acc[4][4];
#pragma unroll
    for (int a = 0; a < 4; a++)
#pragma unroll
        for (int b = 0; b < 4; b++) acc[a][b] = (f32x4){0.f, 0.f, 0.f, 0.f};

#pragma unroll
    for (int nf = 0; nf < 4; nf++) {
        int er = e0 + eb + nf * 16 + l15;
        bf16x8 bv = (bf16x8){0, 0, 0, 0, 0, 0, 0, 0};
        if (lgr < 2 && er < E)
            bv = *(const bf16x8*)(ea16 + (size_t)er * 16 + lgr * 8);
#pragma unroll
        for (int mf = 0; mf < 4; mf++)
            acc[mf][nf] = __builtin_amdgcn_mfma_f32_16x16x32_bf16(
                af[mf], bv, acc[mf][nf], 0, 0, 0);
    }

    // write proj tile to LDS (bf16): reg r -> feature fb+mf*16+lgr*4+r,
    // edge eb+nf*16+l15
#pragma unroll
    for (int nf = 0; nf < 4; nf++) {
        int edge = eb + nf * 16 + l15;
#pragma unroll
        for (int mf = 0; mf < 4; mf++) {
            int fpos = fb + mf * 16 + lgr * 4;
            f32x4 v = acc[mf][nf];
            uint2 p;
            p.x = pk(v[0], v[1]);
            p.y = pk(v[2], v[3]);
            *(uint2*)(&msg[edge * LDF + fpos]) = p;
        }
    }
    __syncthreads();

    // ---- phase 2: gather + relu + run-length segment sum
    const int f    = (D == 128) ? (t & 127) : t;
    const int eh   = (D == 128) ? (t >> 7) * 64 : 0;
    const int lim  = (E - e0 < EPB) ? (E - e0) : EPB;
    int ebeg = eh;
    int eend = (eh + 64 < lim) ? (eh + 64) : lim;
    if (ebeg < eend) {
        const float bef = be[f];
        int cur = dst_s[ebeg];
        float a = 0.f;
#pragma unroll 4
        for (int e = ebeg; e < eend; ++e) {
            int d = dst_s[e];
            if (d != cur) {
                atomicAdd(&agg[(size_t)cur * D + f], a);
                a = 0.f; cur = d;
            }
            float pv = bf2f(msg[e * LDF + f]);
            float hv = bf2f(hbf[(size_t)src_s[e] * D + f]);
            a += fmaxf(pv + hv + bef, 0.f);
        }
        atomicAdd(&agg[(size_t)cur * D + f], a);
    }
}

// ---------------- W transpose + bf16 convert: W[K,256] f32 -> Wt[256,K] bf16
__global__ __launch_bounds__(THREADS) void wtrans_kernel(
    const float* __restrict__ W, unsigned short* __restrict__ Wt, int K)
{
    __shared__ float tile[32][33];
    const int kb = blockIdx.x * 32, nb = blockIdx.y * 32;
    const int tx = threadIdx.x & 31, ty = threadIdx.x >> 5;
#pragma unroll
    for (int i = ty; i < 32; i += 8)
        tile[i][tx] = W[(size_t)(kb + i) * 256 + nb + tx];
    __syncthreads();
#pragma unroll
    for (int i = ty; i < 32; i += 8)
        Wt[(size_t)(nb + i) * K + kb + tx] = f2bf(tile[tx][i]);
}

// ---------------- MFMA node-MLP GEMM (bf16 h in, bf16 out):
// out[r][n] = relu( A[r][:] @ Wt[n][:] + bias[n] )
// MODE 0: A = (1+eps)*hin + agg(f32)    MODE 1: A = hin
template<int K, int MODE>
__global__ __launch_bounds__(THREADS) void mfma_mlp_kernel(
    const unsigned short* __restrict__ hin,   // [nrows, K] bf16
    const float* __restrict__ agg,            // [nrows, K] f32 (MODE 0)
    const unsigned short* __restrict__ Wt,    // [256, K] bf16
    const float* __restrict__ bias,           // [256]
    const float* __restrict__ epsp,           // [1] (MODE 0)
    unsigned short* __restrict__ out,         // [nrows, 256] bf16
    int nrows)
{
    constexpr int BM = 128, BK = 64;
    constexpr int LDR = BK + 8;
    __shared__ short As[BM * LDR];
    __shared__ short Bs[128 * LDR];

    const int t    = threadIdx.x;
    const int lane = t & 63;
    const int wid  = t >> 6;
    const int wm   = wid >> 1, wn = wid & 1;
    const int l15  = lane & 15, lgr = lane >> 4;

    const int r0 = blockIdx.x * BM;
    const int n0 = blockIdx.y * 128;

    float scale = 1.0f;
    if (MODE == 0) scale = 1.0f + epsp[0];

    f32x4 acc[4][4];
#pragma unroll
    for (int a = 0; a < 4; a++)
#pragma unroll
        for (int b = 0; b < 4; b++) acc[a][b] = (f32x4){0.f, 0.f, 0.f, 0.f};

    for (int k0 = 0; k0 < K; k0 += BK) {
        // ---- stage A
#pragma unroll
        for (int c = 0; c < 4; c++) {
            int idx = t + c * THREADS;
            int r   = idx >> 3;
            int kq  = idx & 7;
            int row = r0 + r;
            uint4 o = make_uint4(0, 0, 0, 0);
            if (row < nrows) {
                size_t g = (size_t)row * K + k0 + kq * 8;
                uint4 hv = *(const uint4*)(hin + g);
                if (MODE == 0) {
                    float4 a0 = *(const float4*)(agg + g);
                    float4 a1 = *(const float4*)(agg + g + 4);
                    o.x = pk(scale * bflo(hv.x) + a0.x, scale * bfhi(hv.x) + a0.y);
                    o.y = pk(scale * bflo(hv.y) + a0.z, scale * bfhi(hv.y) + a0.w);
                    o.z = pk(scale * bflo(hv.z) + a1.x, scale * bfhi(hv.z) + a1.y);
                    o.w = pk(scale * bflo(hv.w) + a1.z, scale * bfhi(hv.w) + a1.w);
                } else {
                    o = hv;
                }
            }
            *(uint4*)(&As[r * LDR + kq * 8]) = o;
        }
        // ---- stage B
#pragma unroll
        for (int c = 0; c < 4; c++) {
            int idx = t + c * THREADS;
            int n   = idx >> 3;
            int kq  = idx & 7;
            uint4 w = *(const uint4*)(Wt + (size_t)(n0 + n) * K + k0 + kq * 8);
            *(uint4*)(&Bs[n * LDR + kq * 8]) = w;
        }
        __syncthreads();

#pragma unroll
        for (int ks = 0; ks < 2; ks++) {
            bf16x8 af[4], bfr[4];
#pragma unroll
            for (int mf = 0; mf < 4; mf++)
                af[mf] = *(const bf16x8*)(&As[(wm * 64 + mf * 16 + l15) * LDR + ks * 32 + lgr * 8]);
#pragma unroll
            for (int nf = 0; nf < 4; nf++)
                bfr[nf] = *(const bf16x8*)(&Bs[(wn * 64 + nf * 16 + l15) * LDR + ks * 32 + lgr * 8]);
#pragma unroll
            for (int mf = 0; mf < 4; mf++)
#pragma unroll
                for (int nf = 0; nf < 4; nf++)
                    acc[mf][nf] = __builtin_amdgcn_mfma_f32_16x16x32_bf16(
                        af[mf], bfr[nf], acc[mf][nf], 0, 0, 0);
        }
        __syncthreads();
    }

#pragma unroll
    for (int nf = 0; nf < 4; nf++) {
        int col = n0 + wn * 64 + nf * 16 + l15;
        float bcol = bias[col];
#pragma unroll
        for (int mf = 0; mf < 4; mf++) {
            f32x4 v = acc[mf][nf];
#pragma unroll
            for (int r = 0; r < 4; r++) {
                int row = r0 + wm * 64 + mf * 16 + lgr * 4 + r;
                if (row < nrows)
                    out[(size_t)row * 256 + col] = f2bf(fmaxf(v[r] + bcol, 0.f));
            }
        }
    }
}

// ---------------- global add pool
__global__ __launch_bounds__(THREADS) void pool_kernel(
    const unsigned short* __restrict__ hbf,  // [N, 256] bf16
    const int*   __restrict__ batch,         // [N]
    float*       __restrict__ hg,            // [G, 256] f32
    int nnodes)
{
    constexpr int CH = 64;
    __shared__ int b_s[CH];
    const int t  = threadIdx.x;
    const int v0 = blockIdx.x * CH;
    int cnt = nnodes - v0;
    if (cnt > CH) cnt = CH;
    if (cnt <= 0) return;
    if (t < cnt) b_s[t] = batch[v0 + t];
    __syncthreads();

    int curb  = b_s[0];
    float acc = 0.f;
    for (int v = 0; v < cnt; v++) {
        int b = b_s[v];
        if (b != curb) {
            atomicAdd(&hg[(size_t)curb * 256 + t], acc);
            acc = 0.f; curb = b;
        }
        acc += bf2f(hbf[(size_t)(v0 + v) * 256 + t]);
    }
    atomicAdd(&hg[(size_t)curb * 256 + t], acc);
}

// ---------------- Bayesian weight materialization
__global__ void wprep_kernel(const float* __restrict__ mu,
                             const float* __restrict__ ls,
                             const float* __restrict__ eps,
                             float* __restrict__ w, int n)
{
    int i = blockIdx.x * THREADS + threadIdx.x;
    if (i < n) w[i] = mu[i] + expf(ls[i]) * eps[i];
}

// ---------------- head
__global__ __launch_bounds__(THREADS) void head_kernel(
    const float* __restrict__ hg,
    const float* __restrict__ w1,
    const float* __restrict__ h1_bmu, const float* __restrict__ h1_bls,
    const float* __restrict__ eps_b1,
    const float* __restrict__ h2_wmu, const float* __restrict__ h2_wls,
    const float* __restrict__ eps_w2,
    const float* __restrict__ h2_bmu, const float* __restrict__ h2_bls,
    const float* __restrict__ eps_b2,
    float* __restrict__ out)
{
    __shared__ float x_s[256];
    __shared__ float red[256];
    const int t = threadIdx.x;
    const int g = blockIdx.x;

    x_s[t] = hg[(size_t)g * 256 + t];
    __syncthreads();

    float acc = h1_bmu[t] + expf(h1_bls[t]) * eps_b1[t];
    for (int kk = 0; kk < 256; kk++) acc += x_s[kk] * w1[kk * 256 + t];
    float h1v = acc / (1.f + expf(-acc));

    float w2a = h2_wmu[t * 2 + 0] + expf(h2_wls[t * 2 + 0]) * eps_w2[t * 2 + 0];
    float w2b = h2_wmu[t * 2 + 1] + expf(h2_wls[t * 2 + 1]) * eps_w2[t * 2 + 1];

    red[t] = h1v * w2a;
    __syncthreads();
    for (int s = 128; s > 0; s >>= 1) {
        if (t < s) red[t] += red[t + s];
        __syncthreads();
    }
    if (t == 0) out[(size_t)g * 2 + 0] = red[0] + h2_bmu[0] + expf(h2_bls[0]) * eps_b2[0];
    __syncthreads();

    red[t] = h1v * w2b;
    __syncthreads();
    for (int s = 128; s > 0; s >>= 1) {
        if (t < s) red[t] += red[t + s];
        __syncthreads();
    }
    if (t == 0) out[(size_t)g * 2 + 1] = red[0] + h2_bmu[1] + expf(h2_bls[1]) * eps_b2[1];
}

// ---------------------------------------------------------------------------
extern "C" void kernel_launch(void* const* d_in, const int* in_sizes, int n_in,
                              void* d_out, int out_size, void* d_ws, size_t ws_size,
                              hipStream_t stream)
{
    const float* x         = (const float*)d_in[0];
    const float* edge_attr = (const float*)d_in[1];
    const int*   ei        = (const int*)d_in[2];
    const int*   batch     = (const int*)d_in[3];

    const float* We[3]  = { (const float*)d_in[4],  (const float*)d_in[11], (const float*)d_in[18] };
    const float* be[3]  = { (const float*)d_in[5],  (const float*)d_in[12], (const float*)d_in[19] };
    const float* W1[3]  = { (const float*)d_in[6],  (const float*)d_in[13], (const float*)d_in[20] };
    const float* b1[3]  = { (const float*)d_in[7],  (const float*)d_in[14], (const float*)d_in[21] };
    const float* W2[3]  = { (const float*)d_in[8],  (const float*)d_in[15], (const float*)d_in[22] };
    const float* b2[3]  = { (const float*)d_in[9],  (const float*)d_in[16], (const float*)d_in[23] };
    const float* epsl[3]= { (const float*)d_in[10], (const float*)d_in[17], (const float*)d_in[24] };

    const float* h1_wmu = (const float*)d_in[25];
    const float* h1_wls = (const float*)d_in[26];
    const float* h1_bmu = (const float*)d_in[27];
    const float* h1_bls = (const float*)d_in[28];
    const float* h2_wmu = (const float*)d_in[29];
    const float* h2_wls = (const float*)d_in[30];
    const float* h2_bmu = (const float*)d_in[31];
    const float* h2_bls = (const float*)d_in[32];
    const float* eps_w1 = (const float*)d_in[33];
    const float* eps_b1 = (const float*)d_in[34];
    const float* eps_w2 = (const float*)d_in[35];
    const float* eps_b2 = (const float*)d_in[36];

    const int N = in_sizes[0] / 128;
    const int E = in_sizes[1] / 16;
    const int G = out_size / 2;

    // ---- carve workspace (256B aligned chunks)
    uintptr_t p = (uintptr_t)d_ws;
    auto carve = [&](size_t bytes) -> void* {
        void* r = (void*)p;
        p = (p + bytes + 255) & ~(uintptr_t)255;
        return r;
    };
    float* hg      = (float*)carve((size_t)G * 256 * 4);
    float* w1buf   = (float*)carve(256 * 256 * 4);
    float* aggf    = (float*)carve((size_t)N * 256 * 4);
    int*   rowptr  = (int*)carve((size_t)(N + 1) * 4);
    int*   cursor  = (int*)carve((size_t)N * 4);
    int*   csr_src = (int*)carve((size_t)E * 4);
    int*   csr_dst = (int*)carve((size_t)E * 4);
    int*   csr_eid = (int*)carve((size_t)E * 4);
    unsigned short* ea16  = (unsigned short*)carve((size_t)E * 16 * 2);
    unsigned short* hbf   = (unsigned short*)carve((size_t)N * 256 * 2);
    unsigned short* tmpbf = (unsigned short*)carve((size_t)N * 256 * 2);
    unsigned short* xbf   = (unsigned short*)carve((size_t)N * 128 * 2);
    unsigned short* wep[3];
    wep[0] = (unsigned short*)carve(128 * 32 * 2);
    wep[1] = (unsigned short*)carve(256 * 32 * 2);
    wep[2] = (unsigned short*)carve(256 * 32 * 2);
    unsigned short* wt1[3], *wt2[3];
    wt1[0] = (unsigned short*)carve(256 * 128 * 2);
    for (int l = 0; l < 3; l++) {
        if (l) wt1[l] = (unsigned short*)carve(256 * 256 * 2);
        wt2[l] = (unsigned short*)carve(256 * 256 * 2);
    }

    const int eblocks     = (E + THREADS - 1) / THREADS;
    const int pool_blocks = (N + 63) / 64;
    const dim3 ggrid((N + 127) / 128, 2);

    float* out = (float*)d_out;

    // ---- build CSR once
    hipMemsetAsync(cursor, 0, (size_t)N * sizeof(int), stream);
    hist_kernel<<<eblocks, THREADS, 0, stream>>>(ei, cursor, E);
    scan_kernel<<<1, 1024, 0, stream>>>(cursor, rowptr, N);
    hipMemsetAsync(cursor, 0, (size_t)N * sizeof(int), stream);
    fill_kernel<<<eblocks, THREADS, 0, stream>>>(ei, rowptr, cursor, csr_src, csr_dst, csr_eid, E);
    easort_kernel<<<eblocks, THREADS, 0, stream>>>(edge_attr, csr_eid, ea16, E);
    xprep_kernel<<<(N * 32 + THREADS - 1) / THREADS, THREADS, 0, stream>>>(x, xbf, N * 32);

    // ---- weight prep
    wetrans_kernel<<<1, 128, 0, stream>>>(We[0], wep[0], 128);
    wetrans_kernel<<<1, 256, 0, stream>>>(We[1], wep[1], 256);
    wetrans_kernel<<<1, 256, 0, stream>>>(We[2], wep[2], 256);
    wtrans_kernel<<<dim3(4, 8), THREADS, 0, stream>>>(W1[0], wt1[0], 128);
    wtrans_kernel<<<dim3(8, 8), THREADS, 0, stream>>>(W2[0], wt2[0], 256);
    for (int l = 1; l < 3; l++) {
        wtrans_kernel<<<dim3(8, 8), THREADS, 0, stream>>>(W1[l], wt1[l], 256);
        wtrans_kernel<<<dim3(8, 8), THREADS, 0, stream>>>(W2[l], wt2[l], 256);
    }

    // ---- layer 0 (d = 128, h = xbf)
    hipMemsetAsync(aggf, 0, (size_t)N * 128 * sizeof(float), stream);
    edge_agg_kernel<128><<<(E + 127) / 128, THREADS, 0, stream>>>(
        xbf, ea16, csr_src, csr_dst, wep[0], be[0], aggf, E);
    mfma_mlp_kernel<128, 0><<<ggrid, THREADS, 0, stream>>>(
        xbf, aggf, wt1[0], b1[0], epsl[0], tmpbf, N);
    mfma_mlp_kernel<256, 1><<<ggrid, THREADS, 0, stream>>>(
        tmpbf, nullptr, wt2[0], b2[0], nullptr, hbf, N);

    // ---- layers 1, 2 (d = 256)
    for (int l = 1; l < 3; l++) {
        hipMemsetAsync(aggf, 0, (size_t)N * 256 * sizeof(float), stream);
        edge_agg_kernel<256><<<(E + 63) / 64, THREADS, 0, stream>>>(
            hbf, ea16, csr_src, csr_dst, wep[l], be[l], aggf, E);
        mfma_mlp_kernel<256, 0><<<ggrid, THREADS, 0, stream>>>(
            hbf, aggf, wt1[l], b1[l], epsl[l], tmpbf, N);
        mfma_mlp_kernel<256, 1><<<ggrid, THREADS, 0, stream>>>(
            tmpbf, nullptr, wt2[l], b2[l], nullptr, hbf, N);
    }

    // ---- global add pool -> hg
    hipMemsetAsync(hg, 0, (size_t)G * 256 * sizeof(float), stream);
    pool_kernel<<<pool_blocks, THREADS, 0, stream>>>(hbf, batch, hg, N);

    // ---- Bayesian head
    wprep_kernel<<<(256 * 256 + THREADS - 1) / THREADS, THREADS, 0, stream>>>(
        h1_wmu, h1_wls, eps_w1, w1buf, 256 * 256);
    head_kernel<<<G, THREADS, 0, stream>>>(
        hg, w1buf, h1_bmu, h1_bls, eps_b1,
        h2_wmu, h2_wls, eps_w2, h2_bmu, h2_bls, eps_b2, out);
}